// Round 1
// baseline (1382.656 us; speedup 1.0000x reference)
//
#include <hip/hip_runtime.h>
#include <cstdint>

#define NLEV 16
#define TMASK ((1u << 19) - 1u)

// res[l] = ceil(16 * 1.2^l), computed in float64 to match numpy exactly
__constant__ int c_res[NLEV] = {16, 20, 24, 28, 34, 40, 48, 58, 69, 83,
                                100, 119, 143, 172, 206, 247};

__global__ __launch_bounds__(256) void grid_enc_kernel(
    const float* __restrict__ x,
    const float* __restrict__ tab_s,
    const float* __restrict__ tab_t,
    const float* __restrict__ tab_m,
    float* __restrict__ out, int N)
{
    int tid = blockIdx.x * blockDim.x + threadIdx.x;
    if (tid >= N * NLEV) return;
    int n = tid >> 4;   // point index
    int l = tid & 15;   // level index (fast dim -> coalesced output)

    float x0 = x[n * 4 + 0];
    float x1 = x[n * 4 + 1];
    float x2 = x[n * 4 + 2];
    float x3 = x[n * 4 + 3];

    // ---- m: nearest-neighbor lookup, tiled dense 128^3, then sigmoid ----
    float one_m;
    {
        float q0 = rintf(x0 * 127.0f);   // round-half-even matches jnp.rint
        float q1 = rintf(x1 * 127.0f);
        float q2 = rintf(x2 * 127.0f);
        q0 = fminf(fmaxf(q0, 0.0f), 127.0f);
        q1 = fminf(fmaxf(q1, 0.0f), 127.0f);
        q2 = fminf(fmaxf(q2, 0.0f), 127.0f);
        uint32_t idx = (uint32_t)q0 + ((uint32_t)q1 << 7) + ((uint32_t)q2 << 14);
        float v = tab_m[idx];
        float m = 1.0f / (1.0f + expf(-v));
        one_m = 1.0f - m;
    }

    int r = c_res[l];
    uint32_t ru = (uint32_t)r;
    float rf1 = (float)r - 1.0f;

    float p0 = x0 * rf1, p1 = x1 * rf1, p2 = x2 * rf1, p3 = x3 * rf1;
    float f0 = floorf(p0), f1 = floorf(p1), f2 = floorf(p2), f3 = floorf(p3);
    float w0 = p0 - f0, w1 = p1 - f1, w2 = p2 - f2, w3 = p3 - f3;

    const float2* __restrict__ ts2 = (const float2*)tab_s + ((size_t)l << 19);
    const float2* __restrict__ tt2 = (const float2*)tab_t + ((size_t)l << 19);

    const bool s_direct = (l <= 8);  // res^3 <= 2^19  (res <= 80)
    const bool t_direct = (l <= 2);  // res^4 <= 2^19  (res <= 26)

    // ---- s: 3-D trilinear, 8 corners ----
    float s0 = 0.0f, s1 = 0.0f;
    #pragma unroll
    for (int corner = 0; corner < 8; ++corner) {
        float o0 = (float)(corner & 1);
        float o1 = (float)((corner >> 1) & 1);
        float o2 = (float)((corner >> 2) & 1);
        uint32_t c0 = (uint32_t)fminf(f0 + o0, rf1);
        uint32_t c1 = (uint32_t)fminf(f1 + o1, rf1);
        uint32_t c2 = (uint32_t)fminf(f2 + o2, rf1);
        float wt = ((corner & 1) ? w0 : 1.0f - w0)
                 * (((corner >> 1) & 1) ? w1 : 1.0f - w1)
                 * (((corner >> 2) & 1) ? w2 : 1.0f - w2);
        uint32_t idx;
        if (s_direct) {
            idx = c0 + c1 * ru + c2 * ru * ru;
        } else {
            idx = c0 ^ (c1 * 2654435761u) ^ (c2 * 805459861u);
        }
        idx &= TMASK;
        float2 e = ts2[idx];
        s0 += wt * e.x;
        s1 += wt * e.y;
    }

    // ---- t: 4-D quadrilinear, 16 corners ----
    float t0 = 0.0f, t1 = 0.0f;
    #pragma unroll
    for (int corner = 0; corner < 16; ++corner) {
        float o0 = (float)(corner & 1);
        float o1 = (float)((corner >> 1) & 1);
        float o2 = (float)((corner >> 2) & 1);
        float o3 = (float)((corner >> 3) & 1);
        uint32_t c0 = (uint32_t)fminf(f0 + o0, rf1);
        uint32_t c1 = (uint32_t)fminf(f1 + o1, rf1);
        uint32_t c2 = (uint32_t)fminf(f2 + o2, rf1);
        uint32_t c3 = (uint32_t)fminf(f3 + o3, rf1);
        float wt = ((corner & 1) ? w0 : 1.0f - w0)
                 * (((corner >> 1) & 1) ? w1 : 1.0f - w1)
                 * (((corner >> 2) & 1) ? w2 : 1.0f - w2)
                 * (((corner >> 3) & 1) ? w3 : 1.0f - w3);
        uint32_t idx;
        if (t_direct) {
            idx = c0 + ru * (c1 + ru * (c2 + ru * c3));
        } else {
            idx = c0 ^ (c1 * 2654435761u) ^ (c2 * 805459861u) ^ (c3 * 3674653429u);
        }
        idx &= TMASK;
        float2 e = tt2[idx];
        t0 += wt * e.x;
        t1 += wt * e.y;
    }

    size_t o = (size_t)n * 32 + 2 * (size_t)l;
    out[o]     = s0 + t0 * one_m;
    out[o + 1] = s1 + t1 * one_m;
}

extern "C" void kernel_launch(void* const* d_in, const int* in_sizes, int n_in,
                              void* d_out, int out_size, void* d_ws, size_t ws_size,
                              hipStream_t stream) {
    const float* x     = (const float*)d_in[0];
    const float* tab_s = (const float*)d_in[1];
    const float* tab_t = (const float*)d_in[2];
    const float* tab_m = (const float*)d_in[3];
    float* out = (float*)d_out;

    int N = in_sizes[0] / 4;          // 400000
    int total = N * NLEV;             // 6.4M threads
    int blocks = (total + 255) / 256;
    grid_enc_kernel<<<blocks, 256, 0, stream>>>(x, tab_s, tab_t, tab_m, out, N);
}

// Round 2
// 797.770 us; speedup vs baseline: 1.7332x; 1.7332x over previous
//
#include <hip/hip_runtime.h>
#include <cstdint>

#define NLEV 16
#define TMASK ((1u << 19) - 1u)

typedef float f4v __attribute__((ext_vector_type(4)));
typedef float f2v __attribute__((ext_vector_type(2)));

// res[l] = ceil(16 * 1.2^l) in float64 (matches numpy)
__constant__ int c_res[NLEV] = {16, 20, 24, 28, 34, 40, 48, 58, 69, 83,
                                100, 119, 143, 172, 206, 247};

// ---------------- K0: per-point  one_m = 1 - sigmoid(table_m[nearest]) ----
__global__ __launch_bounds__(256) void m_kernel(
    const float* __restrict__ x, const float* __restrict__ tab_m,
    float* __restrict__ one_m, int N)
{
    int n = blockIdx.x * 256 + threadIdx.x;
    if (n >= N) return;
    f4v xv = __builtin_nontemporal_load((const f4v*)x + n);
    float q0 = fminf(fmaxf(rintf(xv.x * 127.0f), 0.0f), 127.0f);
    float q1 = fminf(fmaxf(rintf(xv.y * 127.0f), 0.0f), 127.0f);
    float q2 = fminf(fmaxf(rintf(xv.z * 127.0f), 0.0f), 127.0f);
    uint32_t idx = (uint32_t)q0 + ((uint32_t)q1 << 7) + ((uint32_t)q2 << 14);
    float v = tab_m[idx];
    float m = 1.0f / (1.0f + expf(-v));
    __builtin_nontemporal_store(1.0f - m, one_m + n);
}

// ---------------- K1: t-pass (4-D, 16 corners), level-major --------------
// ws[l*N + n] = t * one_m   (coalesced float2 stores)
__global__ __launch_bounds__(256) void t_kernel(
    const float* __restrict__ x, const float* __restrict__ tab_t,
    const float* __restrict__ one_m, f2v* __restrict__ ws, int N)
{
    int l = blockIdx.x >> 11;                     // 2048 blocks per level
    int n = ((blockIdx.x & 2047) << 8) + threadIdx.x;
    if (n >= N) return;

    f4v xv = __builtin_nontemporal_load((const f4v*)x + n);
    float om = __builtin_nontemporal_load(one_m + n);

    int r = c_res[l];
    uint32_t ru = (uint32_t)r;
    float rf1 = (float)r - 1.0f;

    float p0 = xv.x * rf1, p1 = xv.y * rf1, p2 = xv.z * rf1, p3 = xv.w * rf1;
    float f0 = floorf(p0), f1 = floorf(p1), f2 = floorf(p2), f3 = floorf(p3);
    float w0 = p0 - f0, w1 = p1 - f1, w2 = p2 - f2, w3 = p3 - f3;

    const f2v* __restrict__ tt2 = (const f2v*)tab_t + ((size_t)l << 19);
    const bool direct = (l <= 2);   // res^4 <= 2^19 (res <= 26) -> stride index

    float t0 = 0.0f, t1 = 0.0f;
    #pragma unroll
    for (int corner = 0; corner < 16; ++corner) {
        float o0 = (float)(corner & 1);
        float o1 = (float)((corner >> 1) & 1);
        float o2 = (float)((corner >> 2) & 1);
        float o3 = (float)((corner >> 3) & 1);
        uint32_t c0 = (uint32_t)fminf(f0 + o0, rf1);
        uint32_t c1 = (uint32_t)fminf(f1 + o1, rf1);
        uint32_t c2 = (uint32_t)fminf(f2 + o2, rf1);
        uint32_t c3 = (uint32_t)fminf(f3 + o3, rf1);
        float wt = ((corner & 1) ? w0 : 1.0f - w0)
                 * (((corner >> 1) & 1) ? w1 : 1.0f - w1)
                 * (((corner >> 2) & 1) ? w2 : 1.0f - w2)
                 * (((corner >> 3) & 1) ? w3 : 1.0f - w3);
        uint32_t idx;
        if (direct) {
            idx = c0 + ru * (c1 + ru * (c2 + ru * c3));
        } else {
            idx = c0 ^ (c1 * 2654435761u) ^ (c2 * 805459861u) ^ (c3 * 3674653429u);
        }
        idx &= TMASK;
        f2v e = tt2[idx];
        t0 += wt * e.x;
        t1 += wt * e.y;
    }
    f2v outv; outv.x = t0 * om; outv.y = t1 * om;
    __builtin_nontemporal_store(outv, ws + (size_t)l * N + n);
}

// ---------------- K2: s-pass (3-D, 8 corners), level-major ----------------
// ws[l*N + n] += s
__global__ __launch_bounds__(256) void s_kernel(
    const float* __restrict__ x, const float* __restrict__ tab_s,
    f2v* __restrict__ ws, int N)
{
    int l = blockIdx.x >> 11;
    int n = ((blockIdx.x & 2047) << 8) + threadIdx.x;
    if (n >= N) return;

    f4v xv = __builtin_nontemporal_load((const f4v*)x + n);

    int r = c_res[l];
    uint32_t ru = (uint32_t)r;
    float rf1 = (float)r - 1.0f;

    float p0 = xv.x * rf1, p1 = xv.y * rf1, p2 = xv.z * rf1;
    float f0 = floorf(p0), f1 = floorf(p1), f2 = floorf(p2);
    float w0 = p0 - f0, w1 = p1 - f1, w2 = p2 - f2;

    const f2v* __restrict__ ts2 = (const f2v*)tab_s + ((size_t)l << 19);
    const bool direct = (l <= 8);   // res^3 <= 2^19 (res <= 80)

    float s0 = 0.0f, s1 = 0.0f;
    #pragma unroll
    for (int corner = 0; corner < 8; ++corner) {
        float o0 = (float)(corner & 1);
        float o1 = (float)((corner >> 1) & 1);
        float o2 = (float)((corner >> 2) & 1);
        uint32_t c0 = (uint32_t)fminf(f0 + o0, rf1);
        uint32_t c1 = (uint32_t)fminf(f1 + o1, rf1);
        uint32_t c2 = (uint32_t)fminf(f2 + o2, rf1);
        float wt = ((corner & 1) ? w0 : 1.0f - w0)
                 * (((corner >> 1) & 1) ? w1 : 1.0f - w1)
                 * (((corner >> 2) & 1) ? w2 : 1.0f - w2);
        uint32_t idx;
        if (direct) {
            idx = c0 + ru * (c1 + ru * c2);
        } else {
            idx = c0 ^ (c1 * 2654435761u) ^ (c2 * 805459861u);
        }
        idx &= TMASK;
        f2v e = ts2[idx];
        s0 += wt * e.x;
        s1 += wt * e.y;
    }
    size_t i = (size_t)l * N + n;
    f2v prev = __builtin_nontemporal_load(ws + i);
    f2v outv; outv.x = prev.x + s0; outv.y = prev.y + s1;
    __builtin_nontemporal_store(outv, ws + i);
}

// ---------------- K3: transpose ws (level-major) -> out (point-major) -----
__global__ __launch_bounds__(256) void out_kernel(
    const f2v* __restrict__ ws, f4v* __restrict__ out4, int N)
{
    __shared__ float lds[256 * 33];
    int tid = threadIdx.x;
    int n = (blockIdx.x << 8) + tid;

    if (n < N) {
        #pragma unroll
        for (int l = 0; l < NLEV; ++l) {
            f2v v = __builtin_nontemporal_load(ws + (size_t)l * N + n);
            lds[tid * 33 + 2 * l]     = v.x;
            lds[tid * 33 + 2 * l + 1] = v.y;
        }
    }
    __syncthreads();

    size_t out4base = (size_t)blockIdx.x * 2048;
    size_t limit = (size_t)N * 8;   // total float4s in out
    #pragma unroll
    for (int k = 0; k < 8; ++k) {
        int g = k * 256 + tid;      // float4 index within the block's tile
        size_t G = out4base + g;
        if (G < limit) {
            int p = g >> 3;         // point within tile
            int e = (g & 7) * 4;    // float element within the 32-float row
            f4v v;
            v.x = lds[p * 33 + e];
            v.y = lds[p * 33 + e + 1];
            v.z = lds[p * 33 + e + 2];
            v.w = lds[p * 33 + e + 3];
            __builtin_nontemporal_store(v, out4 + G);
        }
    }
}

// ---------------- fallback: round-1 monolithic kernel ---------------------
__global__ __launch_bounds__(256) void grid_enc_kernel(
    const float* __restrict__ x,
    const float* __restrict__ tab_s,
    const float* __restrict__ tab_t,
    const float* __restrict__ tab_m,
    float* __restrict__ out, int N)
{
    int tid = blockIdx.x * blockDim.x + threadIdx.x;
    if (tid >= N * NLEV) return;
    int n = tid >> 4;
    int l = tid & 15;

    float x0 = x[n * 4 + 0], x1 = x[n * 4 + 1], x2 = x[n * 4 + 2], x3 = x[n * 4 + 3];

    float one_m;
    {
        float q0 = fminf(fmaxf(rintf(x0 * 127.0f), 0.0f), 127.0f);
        float q1 = fminf(fmaxf(rintf(x1 * 127.0f), 0.0f), 127.0f);
        float q2 = fminf(fmaxf(rintf(x2 * 127.0f), 0.0f), 127.0f);
        uint32_t idx = (uint32_t)q0 + ((uint32_t)q1 << 7) + ((uint32_t)q2 << 14);
        float v = tab_m[idx];
        one_m = 1.0f - 1.0f / (1.0f + expf(-v));
    }

    int r = c_res[l];
    uint32_t ru = (uint32_t)r;
    float rf1 = (float)r - 1.0f;
    float p0 = x0 * rf1, p1 = x1 * rf1, p2 = x2 * rf1, p3 = x3 * rf1;
    float f0 = floorf(p0), f1 = floorf(p1), f2 = floorf(p2), f3 = floorf(p3);
    float w0 = p0 - f0, w1 = p1 - f1, w2 = p2 - f2, w3 = p3 - f3;

    const float2* ts2 = (const float2*)tab_s + ((size_t)l << 19);
    const float2* tt2 = (const float2*)tab_t + ((size_t)l << 19);
    const bool s_direct = (l <= 8), t_direct = (l <= 2);

    float s0 = 0.0f, s1 = 0.0f;
    #pragma unroll
    for (int corner = 0; corner < 8; ++corner) {
        float o0 = (float)(corner & 1), o1 = (float)((corner >> 1) & 1), o2 = (float)((corner >> 2) & 1);
        uint32_t c0 = (uint32_t)fminf(f0 + o0, rf1);
        uint32_t c1 = (uint32_t)fminf(f1 + o1, rf1);
        uint32_t c2 = (uint32_t)fminf(f2 + o2, rf1);
        float wt = ((corner & 1) ? w0 : 1.0f - w0) * (((corner >> 1) & 1) ? w1 : 1.0f - w1)
                 * (((corner >> 2) & 1) ? w2 : 1.0f - w2);
        uint32_t idx = s_direct ? (c0 + c1 * ru + c2 * ru * ru)
                                : (c0 ^ (c1 * 2654435761u) ^ (c2 * 805459861u));
        idx &= TMASK;
        float2 e = ts2[idx];
        s0 += wt * e.x; s1 += wt * e.y;
    }

    float t0 = 0.0f, t1 = 0.0f;
    #pragma unroll
    for (int corner = 0; corner < 16; ++corner) {
        float o0 = (float)(corner & 1), o1 = (float)((corner >> 1) & 1);
        float o2 = (float)((corner >> 2) & 1), o3 = (float)((corner >> 3) & 1);
        uint32_t c0 = (uint32_t)fminf(f0 + o0, rf1);
        uint32_t c1 = (uint32_t)fminf(f1 + o1, rf1);
        uint32_t c2 = (uint32_t)fminf(f2 + o2, rf1);
        uint32_t c3 = (uint32_t)fminf(f3 + o3, rf1);
        float wt = ((corner & 1) ? w0 : 1.0f - w0) * (((corner >> 1) & 1) ? w1 : 1.0f - w1)
                 * (((corner >> 2) & 1) ? w2 : 1.0f - w2) * (((corner >> 3) & 1) ? w3 : 1.0f - w3);
        uint32_t idx = t_direct ? (c0 + ru * (c1 + ru * (c2 + ru * c3)))
                                : (c0 ^ (c1 * 2654435761u) ^ (c2 * 805459861u) ^ (c3 * 3674653429u));
        idx &= TMASK;
        float2 e = tt2[idx];
        t0 += wt * e.x; t1 += wt * e.y;
    }

    size_t o = (size_t)n * 32 + 2 * (size_t)l;
    out[o]     = s0 + t0 * one_m;
    out[o + 1] = s1 + t1 * one_m;
}

extern "C" void kernel_launch(void* const* d_in, const int* in_sizes, int n_in,
                              void* d_out, int out_size, void* d_ws, size_t ws_size,
                              hipStream_t stream) {
    const float* x     = (const float*)d_in[0];
    const float* tab_s = (const float*)d_in[1];
    const float* tab_t = (const float*)d_in[2];
    const float* tab_m = (const float*)d_in[3];
    float* out = (float*)d_out;

    int N = in_sizes[0] / 4;                        // 400000
    size_t wm_bytes = (((size_t)N * 4) + 255) & ~(size_t)255;
    size_t wc_bytes = (size_t)N * NLEV * 2 * 4;     // 51.2 MB
    int nblk = (N + 255) / 256;

    if (ws_size >= wm_bytes + wc_bytes) {
        float* wm = (float*)d_ws;
        f2v*   wc = (f2v*)((char*)d_ws + wm_bytes);
        m_kernel<<<nblk, 256, 0, stream>>>(x, tab_m, wm, N);
        t_kernel<<<NLEV * 2048, 256, 0, stream>>>(x, tab_t, wm, wc, N);
        s_kernel<<<NLEV * 2048, 256, 0, stream>>>(x, tab_s, wc, N);
        out_kernel<<<nblk, 256, 0, stream>>>(wc, (f4v*)out, N);
    } else {
        int total = N * NLEV;
        grid_enc_kernel<<<(total + 255) / 256, 256, 0, stream>>>(x, tab_s, tab_t, tab_m, out, N);
    }
}

// Round 3
// 791.734 us; speedup vs baseline: 1.7464x; 1.0076x over previous
//
#include <hip/hip_runtime.h>
#include <cstdint>

#define NLEV 16
#define TMASK ((1u << 19) - 1u)

typedef float f4v __attribute__((ext_vector_type(4)));
typedef float f2v __attribute__((ext_vector_type(2)));
typedef uint32_t u2v __attribute__((ext_vector_type(2)));

// res[l] = ceil(16 * 1.2^l) in float64 (matches numpy)
__constant__ int c_res[NLEV] = {16, 20, 24, 28, 34, 40, 48, 58, 69, 83,
                                100, 119, 143, 172, 206, 247};

__device__ __forceinline__ float bf_lo(uint32_t e) { return __uint_as_float(e << 16); }
__device__ __forceinline__ float bf_hi(uint32_t e) { return __uint_as_float(e & 0xFFFF0000u); }
__device__ __forceinline__ uint32_t rne16(float f) {
    uint32_t u = __float_as_uint(f);
    return (u + 0x7fffu + ((u >> 16) & 1u)) >> 16;
}

// ---- K-1: pack fp32 float2 entries -> one dword (2 x bf16, RNE) ----------
__global__ __launch_bounds__(256) void conv_kernel(
    const f4v* __restrict__ src_s, const f4v* __restrict__ src_t,
    u2v* __restrict__ dst_s, u2v* __restrict__ dst_t, int half)
{
    int i = blockIdx.x * 256 + threadIdx.x;           // one f4 = 2 entries
    const f4v* src = (i < half) ? src_s : src_t;
    u2v* dst = (i < half) ? dst_s : dst_t;
    int j = (i < half) ? i : i - half;
    if (j < half) {
        f4v v = __builtin_nontemporal_load(src + j);
        u2v o;
        o.x = rne16(v.x) | (rne16(v.y) << 16);
        o.y = rne16(v.z) | (rne16(v.w) << 16);
        __builtin_nontemporal_store(o, dst + j);
    }
}

// ---- K0: per-point  one_m = 1 - sigmoid(table_m[nearest]) ----------------
__global__ __launch_bounds__(256) void m_kernel(
    const float* __restrict__ x, const float* __restrict__ tab_m,
    float* __restrict__ one_m, int N)
{
    int n = blockIdx.x * 256 + threadIdx.x;
    if (n >= N) return;
    f4v xv = __builtin_nontemporal_load((const f4v*)x + n);
    float q0 = fminf(fmaxf(rintf(xv.x * 127.0f), 0.0f), 127.0f);
    float q1 = fminf(fmaxf(rintf(xv.y * 127.0f), 0.0f), 127.0f);
    float q2 = fminf(fmaxf(rintf(xv.z * 127.0f), 0.0f), 127.0f);
    uint32_t idx = (uint32_t)q0 + ((uint32_t)q1 << 7) + ((uint32_t)q2 << 14);
    float v = tab_m[idx];
    float m = 1.0f / (1.0f + expf(-v));
    __builtin_nontemporal_store(1.0f - m, one_m + n);
}

// ---- K1: fused s+t per level, bf16 (PK) or fp32 tables -------------------
// level = blockIdx & 15  ->  XCD j sees only levels {j, j+8} (round-robin
// block->XCD dispatch): 2 x 2MB bf16 tables stay L2-resident per XCD.
template<bool PK>
__global__ __launch_bounds__(256) void st_kernel(
    const float* __restrict__ x,
    const void* __restrict__ tab_s,
    const void* __restrict__ tab_t,
    const float* __restrict__ one_m,
    f2v* __restrict__ ws, int N)
{
    int l = blockIdx.x & 15;
    int n = ((blockIdx.x >> 4) << 8) + threadIdx.x;
    if (n >= N) return;

    f4v xv = __builtin_nontemporal_load((const f4v*)x + n);
    float om = __builtin_nontemporal_load(one_m + n);

    int r = c_res[l];
    uint32_t ru = (uint32_t)r;
    float rf1 = (float)r - 1.0f;

    float p0 = xv.x * rf1, p1 = xv.y * rf1, p2 = xv.z * rf1, p3 = xv.w * rf1;
    float f0 = floorf(p0), f1 = floorf(p1), f2 = floorf(p2), f3 = floorf(p3);
    float w0 = p0 - f0, w1 = p1 - f1, w2 = p2 - f2, w3 = p3 - f3;
    uint32_t c0a = (uint32_t)f0;     // c0a+1 <= r-1 except w0==0 edge (weight 0)

    const bool s_direct = (l <= 8);  // res^3 <= 2^19
    const bool t_direct = (l <= 2);  // res^4 <= 2^19

    // ---------------- t: 8 corner-pairs along dim0 ----------------
    float t0 = 0.0f, t1 = 0.0f;
    {
        const uint32_t* tt = (const uint32_t*)tab_t + ((size_t)l << 19);
        const f2v* tt2 = (const f2v*)tab_t + ((size_t)l << 19);
        #pragma unroll
        for (int pi = 0; pi < 8; ++pi) {
            float o1 = (float)(pi & 1);
            float o2 = (float)((pi >> 1) & 1);
            float o3 = (float)((pi >> 2) & 1);
            uint32_t c1 = (uint32_t)fminf(f1 + o1, rf1);
            uint32_t c2 = (uint32_t)fminf(f2 + o2, rf1);
            uint32_t c3 = (uint32_t)fminf(f3 + o3, rf1);
            float bw = ((pi & 1) ? w1 : 1.0f - w1)
                     * (((pi >> 1) & 1) ? w2 : 1.0f - w2)
                     * (((pi >> 2) & 1) ? w3 : 1.0f - w3);
            uint32_t idxa, idxb; bool same;
            if (t_direct) {
                uint32_t base = ru * (c1 + ru * (c2 + ru * c3));
                idxa = base + c0a; idxb = idxa + 1; same = !(idxa & 1);
            } else {
                uint32_t hh = (c1 * 2654435761u) ^ (c2 * 805459861u) ^ (c3 * 3674653429u);
                idxa = (c0a ^ hh) & TMASK;
                idxb = ((c0a + 1) ^ hh) & TMASK;
                same = !(c0a & 1);
            }
            float wa = bw * (1.0f - w0), wb = bw * w0;
            if (PK) {
                u2v pe = *(const u2v*)(tt + (idxa & ~1u));
                uint32_t ea = (idxa & 1) ? pe.y : pe.x;
                uint32_t eb = (idxa & 1) ? pe.x : pe.y;
                if (!same) eb = tt[idxb];
                t0 += wa * bf_lo(ea) + wb * bf_lo(eb);
                t1 += wa * bf_hi(ea) + wb * bf_hi(eb);
            } else {
                f4v pe = *(const f4v*)(tt2 + (idxa & ~1u));
                float eax = (idxa & 1) ? pe.z : pe.x, eay = (idxa & 1) ? pe.w : pe.y;
                float ebx = (idxa & 1) ? pe.x : pe.z, eby = (idxa & 1) ? pe.y : pe.w;
                if (!same) { f2v e = tt2[idxb]; ebx = e.x; eby = e.y; }
                t0 += wa * eax + wb * ebx;
                t1 += wa * eay + wb * eby;
            }
        }
    }

    // ---------------- s: 4 corner-pairs along dim0 ----------------
    float s0 = 0.0f, s1 = 0.0f;
    {
        const uint32_t* ts = (const uint32_t*)tab_s + ((size_t)l << 19);
        const f2v* ts2 = (const f2v*)tab_s + ((size_t)l << 19);
        #pragma unroll
        for (int pi = 0; pi < 4; ++pi) {
            float o1 = (float)(pi & 1);
            float o2 = (float)((pi >> 1) & 1);
            uint32_t c1 = (uint32_t)fminf(f1 + o1, rf1);
            uint32_t c2 = (uint32_t)fminf(f2 + o2, rf1);
            float bw = ((pi & 1) ? w1 : 1.0f - w1)
                     * (((pi >> 1) & 1) ? w2 : 1.0f - w2);
            uint32_t idxa, idxb; bool same;
            if (s_direct) {
                uint32_t base = ru * (c1 + ru * c2);
                idxa = base + c0a; idxb = idxa + 1; same = !(idxa & 1);
            } else {
                uint32_t hh = (c1 * 2654435761u) ^ (c2 * 805459861u);
                idxa = (c0a ^ hh) & TMASK;
                idxb = ((c0a + 1) ^ hh) & TMASK;
                same = !(c0a & 1);
            }
            float wa = bw * (1.0f - w0), wb = bw * w0;
            if (PK) {
                u2v pe = *(const u2v*)(ts + (idxa & ~1u));
                uint32_t ea = (idxa & 1) ? pe.y : pe.x;
                uint32_t eb = (idxa & 1) ? pe.x : pe.y;
                if (!same) eb = ts[idxb];
                s0 += wa * bf_lo(ea) + wb * bf_lo(eb);
                s1 += wa * bf_hi(ea) + wb * bf_hi(eb);
            } else {
                f4v pe = *(const f4v*)(ts2 + (idxa & ~1u));
                float eax = (idxa & 1) ? pe.z : pe.x, eay = (idxa & 1) ? pe.w : pe.y;
                float ebx = (idxa & 1) ? pe.x : pe.z, eby = (idxa & 1) ? pe.y : pe.w;
                if (!same) { f2v e = ts2[idxb]; ebx = e.x; eby = e.y; }
                s0 += wa * eax + wb * ebx;
                s1 += wa * eay + wb * eby;
            }
        }
    }

    f2v outv; outv.x = s0 + t0 * om; outv.y = s1 + t1 * om;
    __builtin_nontemporal_store(outv, ws + (size_t)l * N + n);
}

// ---- K2: transpose ws (level-major) -> out (point-major) -----------------
__global__ __launch_bounds__(256) void out_kernel(
    const f2v* __restrict__ ws, f4v* __restrict__ out4, int N)
{
    __shared__ float lds[256 * 33];
    int tid = threadIdx.x;
    int n = (blockIdx.x << 8) + tid;

    if (n < N) {
        #pragma unroll
        for (int l = 0; l < NLEV; ++l) {
            f2v v = __builtin_nontemporal_load(ws + (size_t)l * N + n);
            lds[tid * 33 + 2 * l]     = v.x;
            lds[tid * 33 + 2 * l + 1] = v.y;
        }
    }
    __syncthreads();

    size_t out4base = (size_t)blockIdx.x * 2048;
    size_t limit = (size_t)N * 8;
    #pragma unroll
    for (int k = 0; k < 8; ++k) {
        int g = k * 256 + tid;
        size_t G = out4base + g;
        if (G < limit) {
            int p = g >> 3;
            int e = (g & 7) * 4;
            f4v v;
            v.x = lds[p * 33 + e];
            v.y = lds[p * 33 + e + 1];
            v.z = lds[p * 33 + e + 2];
            v.w = lds[p * 33 + e + 3];
            __builtin_nontemporal_store(v, out4 + G);
        }
    }
}

// ---- fallback: monolithic (tiny ws) --------------------------------------
__global__ __launch_bounds__(256) void grid_enc_kernel(
    const float* __restrict__ x,
    const float* __restrict__ tab_s,
    const float* __restrict__ tab_t,
    const float* __restrict__ tab_m,
    float* __restrict__ out, int N)
{
    int tid = blockIdx.x * blockDim.x + threadIdx.x;
    if (tid >= N * NLEV) return;
    int n = tid >> 4, l = tid & 15;
    float x0 = x[n*4+0], x1 = x[n*4+1], x2 = x[n*4+2], x3 = x[n*4+3];
    float one_m;
    {
        float q0 = fminf(fmaxf(rintf(x0*127.0f),0.0f),127.0f);
        float q1 = fminf(fmaxf(rintf(x1*127.0f),0.0f),127.0f);
        float q2 = fminf(fmaxf(rintf(x2*127.0f),0.0f),127.0f);
        uint32_t idx = (uint32_t)q0 + ((uint32_t)q1<<7) + ((uint32_t)q2<<14);
        one_m = 1.0f - 1.0f/(1.0f + expf(-tab_m[idx]));
    }
    int r = c_res[l]; uint32_t ru = (uint32_t)r; float rf1 = (float)r - 1.0f;
    float p0 = x0*rf1, p1 = x1*rf1, p2 = x2*rf1, p3 = x3*rf1;
    float f0 = floorf(p0), f1 = floorf(p1), f2 = floorf(p2), f3 = floorf(p3);
    float w0 = p0-f0, w1 = p1-f1, w2 = p2-f2, w3 = p3-f3;
    const float2* ts2 = (const float2*)tab_s + ((size_t)l<<19);
    const float2* tt2 = (const float2*)tab_t + ((size_t)l<<19);
    const bool sd = (l<=8), td = (l<=2);
    float s0=0,s1=0;
    #pragma unroll
    for (int c = 0; c < 8; ++c) {
        uint32_t c0 = (uint32_t)fminf(f0+(float)(c&1), rf1);
        uint32_t c1 = (uint32_t)fminf(f1+(float)((c>>1)&1), rf1);
        uint32_t c2 = (uint32_t)fminf(f2+(float)((c>>2)&1), rf1);
        float wt = ((c&1)?w0:1.0f-w0)*(((c>>1)&1)?w1:1.0f-w1)*(((c>>2)&1)?w2:1.0f-w2);
        uint32_t idx = sd ? (c0 + c1*ru + c2*ru*ru)
                          : (c0 ^ (c1*2654435761u) ^ (c2*805459861u));
        float2 e = ts2[idx & TMASK]; s0 += wt*e.x; s1 += wt*e.y;
    }
    float t0=0,t1=0;
    #pragma unroll
    for (int c = 0; c < 16; ++c) {
        uint32_t c0 = (uint32_t)fminf(f0+(float)(c&1), rf1);
        uint32_t c1 = (uint32_t)fminf(f1+(float)((c>>1)&1), rf1);
        uint32_t c2 = (uint32_t)fminf(f2+(float)((c>>2)&1), rf1);
        uint32_t c3 = (uint32_t)fminf(f3+(float)((c>>3)&1), rf1);
        float wt = ((c&1)?w0:1.0f-w0)*(((c>>1)&1)?w1:1.0f-w1)
                 *(((c>>2)&1)?w2:1.0f-w2)*(((c>>3)&1)?w3:1.0f-w3);
        uint32_t idx = td ? (c0 + ru*(c1 + ru*(c2 + ru*c3)))
                          : (c0 ^ (c1*2654435761u) ^ (c2*805459861u) ^ (c3*3674653429u));
        float2 e = tt2[idx & TMASK]; t0 += wt*e.x; t1 += wt*e.y;
    }
    size_t o = (size_t)n*32 + 2*(size_t)l;
    out[o] = s0 + t0*one_m; out[o+1] = s1 + t1*one_m;
}

extern "C" void kernel_launch(void* const* d_in, const int* in_sizes, int n_in,
                              void* d_out, int out_size, void* d_ws, size_t ws_size,
                              hipStream_t stream) {
    const float* x     = (const float*)d_in[0];
    const float* tab_s = (const float*)d_in[1];
    const float* tab_t = (const float*)d_in[2];
    const float* tab_m = (const float*)d_in[3];
    float* out = (float*)d_out;

    int N = in_sizes[0] / 4;                            // 400000
    size_t wm_b = (((size_t)N * 4) + 255) & ~(size_t)255;
    size_t wc_b = (size_t)N * NLEV * 8;                 // 51.2 MB
    size_t tb_b = (size_t)NLEV * (1u << 19) * 4;        // 33.55 MB per packed table
    int nchunk = (N + 255) / 256;

    if (ws_size >= wm_b + wc_b + 2 * tb_b) {
        float* wm = (float*)d_ws;
        f2v*   wc = (f2v*)((char*)d_ws + wm_b);
        uint32_t* ps = (uint32_t*)((char*)d_ws + wm_b + wc_b);
        uint32_t* pt = ps + (size_t)NLEV * (1u << 19);
        int half = NLEV * (1 << 19) / 2;                // f4 count per table
        conv_kernel<<<(2 * half + 255) / 256, 256, 0, stream>>>(
            (const f4v*)tab_s, (const f4v*)tab_t, (u2v*)ps, (u2v*)pt, half);
        m_kernel<<<nchunk, 256, 0, stream>>>(x, tab_m, wm, N);
        st_kernel<true><<<nchunk * NLEV, 256, 0, stream>>>(x, ps, pt, wm, wc, N);
        out_kernel<<<nchunk, 256, 0, stream>>>(wc, (f4v*)out, N);
    } else if (ws_size >= wm_b + wc_b) {
        float* wm = (float*)d_ws;
        f2v*   wc = (f2v*)((char*)d_ws + wm_b);
        m_kernel<<<nchunk, 256, 0, stream>>>(x, tab_m, wm, N);
        st_kernel<false><<<nchunk * NLEV, 256, 0, stream>>>(x, tab_s, tab_t, wm, wc, N);
        out_kernel<<<nchunk, 256, 0, stream>>>(wc, (f4v*)out, N);
    } else {
        int total = N * NLEV;
        grid_enc_kernel<<<(total + 255) / 256, 256, 0, stream>>>(x, tab_s, tab_t, tab_m, out, N);
    }
}

// Round 4
// 710.809 us; speedup vs baseline: 1.9452x; 1.1138x over previous
//
#include <hip/hip_runtime.h>
#include <cstdint>

#define NLEV 16
#define TMASK ((1u << 19) - 1u)

typedef float f4v __attribute__((ext_vector_type(4)));
typedef float f2v __attribute__((ext_vector_type(2)));
typedef uint32_t u2v __attribute__((ext_vector_type(2)));

// res[l] = ceil(16 * 1.2^l) in float64 (matches numpy)
__constant__ int c_res[NLEV] = {16, 20, 24, 28, 34, 40, 48, 58, 69, 83,
                                100, 119, 143, 172, 206, 247};

__device__ __forceinline__ float bf_lo(uint32_t e) { return __uint_as_float(e << 16); }
__device__ __forceinline__ float bf_hi(uint32_t e) { return __uint_as_float(e & 0xFFFF0000u); }
__device__ __forceinline__ uint32_t rne16(float f) {
    uint32_t u = __float_as_uint(f);
    return (u + 0x7fffu + ((u >> 16) & 1u)) >> 16;
}

// ---- K-1: pack fp32 float2 entries -> one dword (2 x bf16, RNE) ----------
__global__ __launch_bounds__(256) void conv_kernel(
    const f4v* __restrict__ src_s, const f4v* __restrict__ src_t,
    u2v* __restrict__ dst_s, u2v* __restrict__ dst_t, int half)
{
    int i = blockIdx.x * 256 + threadIdx.x;           // one f4 = 2 entries
    const f4v* src = (i < half) ? src_s : src_t;
    u2v* dst = (i < half) ? dst_s : dst_t;
    int j = (i < half) ? i : i - half;
    if (j < half) {
        f4v v = __builtin_nontemporal_load(src + j);
        u2v o;
        o.x = rne16(v.x) | (rne16(v.y) << 16);
        o.y = rne16(v.z) | (rne16(v.w) << 16);
        __builtin_nontemporal_store(o, dst + j);
    }
}

// ---- K0: per-point  one_m = 1 - sigmoid(table_m[nearest]) ----------------
__global__ __launch_bounds__(256) void m_kernel(
    const float* __restrict__ x, const float* __restrict__ tab_m,
    float* __restrict__ one_m, int N)
{
    int n = blockIdx.x * 256 + threadIdx.x;
    if (n >= N) return;
    f4v xv = __builtin_nontemporal_load((const f4v*)x + n);
    float q0 = fminf(fmaxf(rintf(xv.x * 127.0f), 0.0f), 127.0f);
    float q1 = fminf(fmaxf(rintf(xv.y * 127.0f), 0.0f), 127.0f);
    float q2 = fminf(fmaxf(rintf(xv.z * 127.0f), 0.0f), 127.0f);
    uint32_t idx = (uint32_t)q0 + ((uint32_t)q1 << 7) + ((uint32_t)q2 << 14);
    float v = tab_m[idx];
    float m = 1.0f / (1.0f + expf(-v));
    __builtin_nontemporal_store(1.0f - m, one_m + n);
}

// ---- K1/K2: one table-kind per pass, one level per XCD at a time ---------
// Block mapping: blk' = blk (- half_grid if hi). level = (blk' & 7) + 8*hi.
// With round-robin block->XCD dispatch (XCD = blk % 8, verified by round-2
// FETCH arithmetic), XCD j holds exactly ONE 2MB bf16 table at a time ->
// fully L2-resident. Streaming x/om/ws use nontemporal to avoid evicting it.
template<bool IS_T>
__global__ __launch_bounds__(256) void enc_kernel(
    const float* __restrict__ x,
    const uint32_t* __restrict__ tab,     // packed bf16x2 per entry
    const float* __restrict__ one_m,      // used only when IS_T
    f2v* __restrict__ ws, int N, int half_grid)
{
    int blk = blockIdx.x;
    int hi = (blk >= half_grid) ? 1 : 0;
    int blkp = blk - hi * half_grid;
    int l = (blkp & 7) + hi * 8;
    int n = ((blkp >> 3) << 8) + threadIdx.x;
    if (n >= N) return;

    f4v xv = __builtin_nontemporal_load((const f4v*)x + n);

    int r = c_res[l];
    uint32_t ru = (uint32_t)r;
    float rf1 = (float)r - 1.0f;

    float p0 = xv.x * rf1, p1 = xv.y * rf1, p2 = xv.z * rf1;
    float f0 = floorf(p0), f1 = floorf(p1), f2 = floorf(p2);
    float w0 = p0 - f0, w1 = p1 - f1, w2 = p2 - f2;
    uint32_t c0a = (uint32_t)f0;   // c0a+1 may exceed r-1 only when w0==0 (weight 0)

    const uint32_t* tl = tab + ((size_t)l << 19);

    float a0 = 0.0f, a1 = 0.0f;

    if (IS_T) {
        float p3 = xv.w * rf1;
        float f3 = floorf(p3);
        float w3 = p3 - f3;
        const bool direct = (l <= 2);            // res^4 <= 2^19
        #pragma unroll
        for (int pi = 0; pi < 8; ++pi) {
            float o1 = (float)(pi & 1);
            float o2 = (float)((pi >> 1) & 1);
            float o3 = (float)((pi >> 2) & 1);
            uint32_t c1 = (uint32_t)fminf(f1 + o1, rf1);
            uint32_t c2 = (uint32_t)fminf(f2 + o2, rf1);
            uint32_t c3 = (uint32_t)fminf(f3 + o3, rf1);
            float bw = ((pi & 1) ? w1 : 1.0f - w1)
                     * (((pi >> 1) & 1) ? w2 : 1.0f - w2)
                     * (((pi >> 2) & 1) ? w3 : 1.0f - w3);
            uint32_t idxa, idxb; bool same;
            if (direct) {
                uint32_t base = ru * (c1 + ru * (c2 + ru * c3));
                idxa = base + c0a; idxb = idxa + 1; same = !(idxa & 1);
            } else {
                uint32_t hh = (c1 * 2654435761u) ^ (c2 * 805459861u) ^ (c3 * 3674653429u);
                idxa = (c0a ^ hh) & TMASK;
                idxb = ((c0a + 1) ^ hh) & TMASK;
                same = !(c0a & 1);
            }
            float wa = bw * (1.0f - w0), wb = bw * w0;
            u2v pe = *(const u2v*)(tl + (idxa & ~1u));
            uint32_t ea = (idxa & 1) ? pe.y : pe.x;
            uint32_t eb = (idxa & 1) ? pe.x : pe.y;
            if (!same) eb = tl[idxb];
            a0 += wa * bf_lo(ea) + wb * bf_lo(eb);
            a1 += wa * bf_hi(ea) + wb * bf_hi(eb);
        }
        float om = __builtin_nontemporal_load(one_m + n);
        f2v outv; outv.x = a0 * om; outv.y = a1 * om;
        __builtin_nontemporal_store(outv, ws + (size_t)l * N + n);
    } else {
        const bool direct = (l <= 8);            // res^3 <= 2^19
        #pragma unroll
        for (int pi = 0; pi < 4; ++pi) {
            float o1 = (float)(pi & 1);
            float o2 = (float)((pi >> 1) & 1);
            uint32_t c1 = (uint32_t)fminf(f1 + o1, rf1);
            uint32_t c2 = (uint32_t)fminf(f2 + o2, rf1);
            float bw = ((pi & 1) ? w1 : 1.0f - w1)
                     * (((pi >> 1) & 1) ? w2 : 1.0f - w2);
            uint32_t idxa, idxb; bool same;
            if (direct) {
                uint32_t base = ru * (c1 + ru * c2);
                idxa = base + c0a; idxb = idxa + 1; same = !(idxa & 1);
            } else {
                uint32_t hh = (c1 * 2654435761u) ^ (c2 * 805459861u);
                idxa = (c0a ^ hh) & TMASK;
                idxb = ((c0a + 1) ^ hh) & TMASK;
                same = !(c0a & 1);
            }
            float wa = bw * (1.0f - w0), wb = bw * w0;
            u2v pe = *(const u2v*)(tl + (idxa & ~1u));
            uint32_t ea = (idxa & 1) ? pe.y : pe.x;
            uint32_t eb = (idxa & 1) ? pe.x : pe.y;
            if (!same) eb = tl[idxb];
            a0 += wa * bf_lo(ea) + wb * bf_lo(eb);
            a1 += wa * bf_hi(ea) + wb * bf_hi(eb);
        }
        size_t i = (size_t)l * N + n;
        f2v prev = __builtin_nontemporal_load(ws + i);
        f2v outv; outv.x = prev.x + a0; outv.y = prev.y + a1;
        __builtin_nontemporal_store(outv, ws + i);
    }
}

// ---- K3: transpose ws (level-major) -> out (point-major) -----------------
__global__ __launch_bounds__(256) void out_kernel(
    const f2v* __restrict__ ws, f4v* __restrict__ out4, int N)
{
    __shared__ float lds[256 * 33];
    int tid = threadIdx.x;
    int n = (blockIdx.x << 8) + tid;

    if (n < N) {
        #pragma unroll
        for (int l = 0; l < NLEV; ++l) {
            f2v v = __builtin_nontemporal_load(ws + (size_t)l * N + n);
            lds[tid * 33 + 2 * l]     = v.x;
            lds[tid * 33 + 2 * l + 1] = v.y;
        }
    }
    __syncthreads();

    size_t out4base = (size_t)blockIdx.x * 2048;
    size_t limit = (size_t)N * 8;
    #pragma unroll
    for (int k = 0; k < 8; ++k) {
        int g = k * 256 + tid;
        size_t G = out4base + g;
        if (G < limit) {
            int p = g >> 3;
            int e = (g & 7) * 4;
            f4v v;
            v.x = lds[p * 33 + e];
            v.y = lds[p * 33 + e + 1];
            v.z = lds[p * 33 + e + 2];
            v.w = lds[p * 33 + e + 3];
            __builtin_nontemporal_store(v, out4 + G);
        }
    }
}

// ---- fallback: monolithic (tiny ws) --------------------------------------
__global__ __launch_bounds__(256) void grid_enc_kernel(
    const float* __restrict__ x,
    const float* __restrict__ tab_s,
    const float* __restrict__ tab_t,
    const float* __restrict__ tab_m,
    float* __restrict__ out, int N)
{
    int tid = blockIdx.x * blockDim.x + threadIdx.x;
    if (tid >= N * NLEV) return;
    int n = tid >> 4, l = tid & 15;
    float x0 = x[n*4+0], x1 = x[n*4+1], x2 = x[n*4+2], x3 = x[n*4+3];
    float one_m;
    {
        float q0 = fminf(fmaxf(rintf(x0*127.0f),0.0f),127.0f);
        float q1 = fminf(fmaxf(rintf(x1*127.0f),0.0f),127.0f);
        float q2 = fminf(fmaxf(rintf(x2*127.0f),0.0f),127.0f);
        uint32_t idx = (uint32_t)q0 + ((uint32_t)q1<<7) + ((uint32_t)q2<<14);
        one_m = 1.0f - 1.0f/(1.0f + expf(-tab_m[idx]));
    }
    int r = c_res[l]; uint32_t ru = (uint32_t)r; float rf1 = (float)r - 1.0f;
    float p0 = x0*rf1, p1 = x1*rf1, p2 = x2*rf1, p3 = x3*rf1;
    float f0 = floorf(p0), f1 = floorf(p1), f2 = floorf(p2), f3 = floorf(p3);
    float w0 = p0-f0, w1 = p1-f1, w2 = p2-f2, w3 = p3-f3;
    const float2* ts2 = (const float2*)tab_s + ((size_t)l<<19);
    const float2* tt2 = (const float2*)tab_t + ((size_t)l<<19);
    const bool sd = (l<=8), td = (l<=2);
    float s0=0,s1=0;
    #pragma unroll
    for (int c = 0; c < 8; ++c) {
        uint32_t c0 = (uint32_t)fminf(f0+(float)(c&1), rf1);
        uint32_t c1 = (uint32_t)fminf(f1+(float)((c>>1)&1), rf1);
        uint32_t c2 = (uint32_t)fminf(f2+(float)((c>>2)&1), rf1);
        float wt = ((c&1)?w0:1.0f-w0)*(((c>>1)&1)?w1:1.0f-w1)*(((c>>2)&1)?w2:1.0f-w2);
        uint32_t idx = sd ? (c0 + c1*ru + c2*ru*ru)
                          : (c0 ^ (c1*2654435761u) ^ (c2*805459861u));
        float2 e = ts2[idx & TMASK]; s0 += wt*e.x; s1 += wt*e.y;
    }
    float t0=0,t1=0;
    #pragma unroll
    for (int c = 0; c < 16; ++c) {
        uint32_t c0 = (uint32_t)fminf(f0+(float)(c&1), rf1);
        uint32_t c1 = (uint32_t)fminf(f1+(float)((c>>1)&1), rf1);
        uint32_t c2 = (uint32_t)fminf(f2+(float)((c>>2)&1), rf1);
        uint32_t c3 = (uint32_t)fminf(f3+(float)((c>>3)&1), rf1);
        float wt = ((c&1)?w0:1.0f-w0)*(((c>>1)&1)?w1:1.0f-w1)
                 *(((c>>2)&1)?w2:1.0f-w2)*(((c>>3)&1)?w3:1.0f-w3);
        uint32_t idx = td ? (c0 + ru*(c1 + ru*(c2 + ru*c3)))
                          : (c0 ^ (c1*2654435761u) ^ (c2*805459861u) ^ (c3*3674653429u));
        float2 e = tt2[idx & TMASK]; t0 += wt*e.x; t1 += wt*e.y;
    }
    size_t o = (size_t)n*32 + 2*(size_t)l;
    out[o] = s0 + t0*one_m; out[o+1] = s1 + t1*one_m;
}

extern "C" void kernel_launch(void* const* d_in, const int* in_sizes, int n_in,
                              void* d_out, int out_size, void* d_ws, size_t ws_size,
                              hipStream_t stream) {
    const float* x     = (const float*)d_in[0];
    const float* tab_s = (const float*)d_in[1];
    const float* tab_t = (const float*)d_in[2];
    const float* tab_m = (const float*)d_in[3];
    float* out = (float*)d_out;

    int N = in_sizes[0] / 4;                            // 400000
    size_t wm_b = (((size_t)N * 4) + 255) & ~(size_t)255;
    size_t wc_b = (size_t)N * NLEV * 8;                 // 51.2 MB
    size_t tb_b = (size_t)NLEV * (1u << 19) * 4;        // 33.55 MB per packed table
    int nchunk = (N + 255) / 256;

    if (ws_size >= wm_b + wc_b + 2 * tb_b) {
        float* wm = (float*)d_ws;
        f2v*   wc = (f2v*)((char*)d_ws + wm_b);
        uint32_t* ps = (uint32_t*)((char*)d_ws + wm_b + wc_b);
        uint32_t* pt = ps + (size_t)NLEV * (1u << 19);
        int half = NLEV * (1 << 19) / 2;                // f4 count per table
        int half_grid = 8 * nchunk;
        conv_kernel<<<(2 * half + 255) / 256, 256, 0, stream>>>(
            (const f4v*)tab_s, (const f4v*)tab_t, (u2v*)ps, (u2v*)pt, half);
        m_kernel<<<nchunk, 256, 0, stream>>>(x, tab_m, wm, N);
        enc_kernel<true><<<16 * nchunk, 256, 0, stream>>>(x, pt, wm, wc, N, half_grid);
        enc_kernel<false><<<16 * nchunk, 256, 0, stream>>>(x, ps, wm, wc, N, half_grid);
        out_kernel<<<nchunk, 256, 0, stream>>>(wc, (f4v*)out, N);
    } else {
        int total = N * NLEV;
        grid_enc_kernel<<<(total + 255) / 256, 256, 0, stream>>>(x, tab_s, tab_t, tab_m, out, N);
    }
}

// Round 5
// 684.935 us; speedup vs baseline: 2.0187x; 1.0378x over previous
//
#include <hip/hip_runtime.h>
#include <cstdint>

#define NLEV 16
#define TMASK ((1u << 19) - 1u)

typedef float f4v __attribute__((ext_vector_type(4)));
typedef float f2v __attribute__((ext_vector_type(2)));
typedef uint32_t u2v __attribute__((ext_vector_type(2)));

// res[l] = ceil(16 * 1.2^l) in float64 (matches numpy)
__constant__ int c_res[NLEV] = {16, 20, 24, 28, 34, 40, 48, 58, 69, 83,
                                100, 119, 143, 172, 206, 247};

__device__ __forceinline__ float bf_lo(uint32_t e) { return __uint_as_float(e << 16); }
__device__ __forceinline__ float bf_hi(uint32_t e) { return __uint_as_float(e & 0xFFFF0000u); }
__device__ __forceinline__ uint32_t rne16(float f) {
    uint32_t u = __float_as_uint(f);
    return (u + 0x7fffu + ((u >> 16) & 1u)) >> 16;
}

// ---- K-1: pack fp32 float2 entries -> one dword (2 x bf16, RNE) ----------
__global__ __launch_bounds__(256) void conv_kernel(
    const f4v* __restrict__ src_s, const f4v* __restrict__ src_t,
    u2v* __restrict__ dst_s, u2v* __restrict__ dst_t, int half)
{
    int i = blockIdx.x * 256 + threadIdx.x;           // one f4 = 2 entries
    const f4v* src = (i < half) ? src_s : src_t;
    u2v* dst = (i < half) ? dst_s : dst_t;
    int j = (i < half) ? i : i - half;
    if (j < half) {
        f4v v = __builtin_nontemporal_load(src + j);
        u2v o;
        o.x = rne16(v.x) | (rne16(v.y) << 16);
        o.y = rne16(v.z) | (rne16(v.w) << 16);
        __builtin_nontemporal_store(o, dst + j);
    }
}

// ---- K0: per-point  one_m = 1 - sigmoid(table_m[nearest]) ----------------
__global__ __launch_bounds__(256) void m_kernel(
    const float* __restrict__ x, const float* __restrict__ tab_m,
    float* __restrict__ one_m, int N)
{
    int n = blockIdx.x * 256 + threadIdx.x;
    if (n >= N) return;
    f4v xv = __builtin_nontemporal_load((const f4v*)x + n);
    float q0 = fminf(fmaxf(rintf(xv.x * 127.0f), 0.0f), 127.0f);
    float q1 = fminf(fmaxf(rintf(xv.y * 127.0f), 0.0f), 127.0f);
    float q2 = fminf(fmaxf(rintf(xv.z * 127.0f), 0.0f), 127.0f);
    uint32_t idx = (uint32_t)q0 + ((uint32_t)q1 << 7) + ((uint32_t)q2 << 14);
    float v = tab_m[idx];
    float m = 1.0f / (1.0f + expf(-v));
    __builtin_nontemporal_store(1.0f - m, one_m + n);
}

// ---- K1/K2: one table-kind per pass, one level per XCD at a time ---------
// All gather addresses are data-independent: compute every index first,
// issue ALL pair loads + predicated odd loads into register arrays, THEN
// accumulate. __launch_bounds__(256,4) lifts VGPR cap to 128 so ~17 loads
// stay in flight per wave (MLP), covering ~200cyc L2-hit latency.
template<bool IS_T>
__global__ __launch_bounds__(256, 4) void enc_kernel(
    const float* __restrict__ x,
    const uint32_t* __restrict__ tab,     // packed bf16x2 per entry
    const float* __restrict__ one_m,      // used only when IS_T
    f2v* __restrict__ ws, int N, int half_grid)
{
    const int NP = IS_T ? 8 : 4;          // corner-pairs along dim0

    int blk = blockIdx.x;
    int hi = (blk >= half_grid) ? 1 : 0;
    int blkp = blk - hi * half_grid;
    int l = (blkp & 7) + hi * 8;
    int n = ((blkp >> 3) << 8) + threadIdx.x;
    if (n >= N) return;

    f4v xv = __builtin_nontemporal_load((const f4v*)x + n);

    int r = c_res[l];
    uint32_t ru = (uint32_t)r;
    float rf1 = (float)r - 1.0f;

    float p0 = xv.x * rf1, p1 = xv.y * rf1, p2 = xv.z * rf1;
    float f0 = floorf(p0), f1 = floorf(p1), f2 = floorf(p2);
    float w0 = p0 - f0, w1 = p1 - f1, w2 = p2 - f2;
    uint32_t c0a = (uint32_t)f0;   // c0a+1 may exceed r-1 only when w0==0 (weight 0)

    float p3 = 0.0f, f3 = 0.0f, w3 = 0.0f;
    if (IS_T) { p3 = xv.w * rf1; f3 = floorf(p3); w3 = p3 - f3; }

    const bool direct = IS_T ? (l <= 2) : (l <= 8);
    const uint32_t* tl = tab + ((size_t)l << 19);

    // ---- phase 1: all indices --------------------------------------------
    uint32_t idxa[8];      // primary index (element)
    uint32_t oidx[8];      // secondary index when not same-pair
    uint32_t need[8];      // 1 -> oidx load required
    #pragma unroll
    for (int pi = 0; pi < NP; ++pi) {
        float o1 = (float)(pi & 1);
        float o2 = (float)((pi >> 1) & 1);
        uint32_t c1 = (uint32_t)fminf(f1 + o1, rf1);
        uint32_t c2 = (uint32_t)fminf(f2 + o2, rf1);
        if (direct) {
            uint32_t base;
            if (IS_T) {
                float o3 = (float)((pi >> 2) & 1);
                uint32_t c3 = (uint32_t)fminf(f3 + o3, rf1);
                base = ru * (c1 + ru * (c2 + ru * c3));
            } else {
                base = ru * (c1 + ru * c2);
            }
            uint32_t ia = base + c0a;
            idxa[pi] = ia;
            oidx[pi] = ia + 1;
            need[pi] = ia & 1;            // even -> pair covers both
        } else {
            uint32_t hh = (c1 * 2654435761u) ^ (c2 * 805459861u);
            if (IS_T) {
                float o3 = (float)((pi >> 2) & 1);
                uint32_t c3 = (uint32_t)fminf(f3 + o3, rf1);
                hh ^= c3 * 3674653429u;
            }
            idxa[pi] = (c0a ^ hh) & TMASK;
            oidx[pi] = ((c0a + 1) ^ hh) & TMASK;
            need[pi] = c0a & 1;           // even c0a -> idxb == idxa^1, in pair
        }
    }

    // ---- phase 2: issue ALL loads (pair loads, then predicated odd) ------
    u2v pv[8];
    #pragma unroll
    for (int pi = 0; pi < NP; ++pi)
        pv[pi] = *(const u2v*)(tl + (idxa[pi] & ~1u));
    uint32_t ov[8];
    #pragma unroll
    for (int pi = 0; pi < NP; ++pi)
        if (need[pi]) ov[pi] = tl[oidx[pi]];

    // ---- phase 3: accumulate ---------------------------------------------
    float a0 = 0.0f, a1 = 0.0f;
    float wva = 1.0f - w0, wvb = w0;
    #pragma unroll
    for (int pi = 0; pi < NP; ++pi) {
        float bw = ((pi & 1) ? w1 : 1.0f - w1)
                 * (((pi >> 1) & 1) ? w2 : 1.0f - w2);
        if (IS_T) bw *= (((pi >> 2) & 1) ? w3 : 1.0f - w3);
        uint32_t sw = idxa[pi] & 1;
        uint32_t ea = sw ? pv[pi].y : pv[pi].x;
        uint32_t eb = sw ? pv[pi].x : pv[pi].y;
        if (need[pi]) eb = ov[pi];
        float wa = bw * wva, wb = bw * wvb;
        a0 += wa * bf_lo(ea) + wb * bf_lo(eb);
        a1 += wa * bf_hi(ea) + wb * bf_hi(eb);
    }

    if (IS_T) {
        float om = __builtin_nontemporal_load(one_m + n);
        f2v outv; outv.x = a0 * om; outv.y = a1 * om;
        __builtin_nontemporal_store(outv, ws + (size_t)l * N + n);
    } else {
        size_t i = (size_t)l * N + n;
        f2v prev = __builtin_nontemporal_load(ws + i);
        f2v outv; outv.x = prev.x + a0; outv.y = prev.y + a1;
        __builtin_nontemporal_store(outv, ws + i);
    }
}

// ---- K3: transpose ws (level-major) -> out (point-major) -----------------
__global__ __launch_bounds__(256) void out_kernel(
    const f2v* __restrict__ ws, f4v* __restrict__ out4, int N)
{
    __shared__ float lds[256 * 33];
    int tid = threadIdx.x;
    int n = (blockIdx.x << 8) + tid;

    if (n < N) {
        #pragma unroll
        for (int l = 0; l < NLEV; ++l) {
            f2v v = __builtin_nontemporal_load(ws + (size_t)l * N + n);
            lds[tid * 33 + 2 * l]     = v.x;
            lds[tid * 33 + 2 * l + 1] = v.y;
        }
    }
    __syncthreads();

    size_t out4base = (size_t)blockIdx.x * 2048;
    size_t limit = (size_t)N * 8;
    #pragma unroll
    for (int k = 0; k < 8; ++k) {
        int g = k * 256 + tid;
        size_t G = out4base + g;
        if (G < limit) {
            int p = g >> 3;
            int e = (g & 7) * 4;
            f4v v;
            v.x = lds[p * 33 + e];
            v.y = lds[p * 33 + e + 1];
            v.z = lds[p * 33 + e + 2];
            v.w = lds[p * 33 + e + 3];
            __builtin_nontemporal_store(v, out4 + G);
        }
    }
}

// ---- fallback: monolithic (tiny ws) --------------------------------------
__global__ __launch_bounds__(256) void grid_enc_kernel(
    const float* __restrict__ x,
    const float* __restrict__ tab_s,
    const float* __restrict__ tab_t,
    const float* __restrict__ tab_m,
    float* __restrict__ out, int N)
{
    int tid = blockIdx.x * blockDim.x + threadIdx.x;
    if (tid >= N * NLEV) return;
    int n = tid >> 4, l = tid & 15;
    float x0 = x[n*4+0], x1 = x[n*4+1], x2 = x[n*4+2], x3 = x[n*4+3];
    float one_m;
    {
        float q0 = fminf(fmaxf(rintf(x0*127.0f),0.0f),127.0f);
        float q1 = fminf(fmaxf(rintf(x1*127.0f),0.0f),127.0f);
        float q2 = fminf(fmaxf(rintf(x2*127.0f),0.0f),127.0f);
        uint32_t idx = (uint32_t)q0 + ((uint32_t)q1<<7) + ((uint32_t)q2<<14);
        one_m = 1.0f - 1.0f/(1.0f + expf(-tab_m[idx]));
    }
    int r = c_res[l]; uint32_t ru = (uint32_t)r; float rf1 = (float)r - 1.0f;
    float p0 = x0*rf1, p1 = x1*rf1, p2 = x2*rf1, p3 = x3*rf1;
    float f0 = floorf(p0), f1 = floorf(p1), f2 = floorf(p2), f3 = floorf(p3);
    float w0 = p0-f0, w1 = p1-f1, w2 = p2-f2, w3 = p3-f3;
    const float2* ts2 = (const float2*)tab_s + ((size_t)l<<19);
    const float2* tt2 = (const float2*)tab_t + ((size_t)l<<19);
    const bool sd = (l<=8), td = (l<=2);
    float s0=0,s1=0;
    #pragma unroll
    for (int c = 0; c < 8; ++c) {
        uint32_t c0 = (uint32_t)fminf(f0+(float)(c&1), rf1);
        uint32_t c1 = (uint32_t)fminf(f1+(float)((c>>1)&1), rf1);
        uint32_t c2 = (uint32_t)fminf(f2+(float)((c>>2)&1), rf1);
        float wt = ((c&1)?w0:1.0f-w0)*(((c>>1)&1)?w1:1.0f-w1)*(((c>>2)&1)?w2:1.0f-w2);
        uint32_t idx = sd ? (c0 + c1*ru + c2*ru*ru)
                          : (c0 ^ (c1*2654435761u) ^ (c2*805459861u));
        float2 e = ts2[idx & TMASK]; s0 += wt*e.x; s1 += wt*e.y;
    }
    float t0=0,t1=0;
    #pragma unroll
    for (int c = 0; c < 16; ++c) {
        uint32_t c0 = (uint32_t)fminf(f0+(float)(c&1), rf1);
        uint32_t c1 = (uint32_t)fminf(f1+(float)((c>>1)&1), rf1);
        uint32_t c2 = (uint32_t)fminf(f2+(float)((c>>2)&1), rf1);
        uint32_t c3 = (uint32_t)fminf(f3+(float)((c>>3)&1), rf1);
        float wt = ((c&1)?w0:1.0f-w0)*(((c>>1)&1)?w1:1.0f-w1)
                 *(((c>>2)&1)?w2:1.0f-w2)*(((c>>3)&1)?w3:1.0f-w3);
        uint32_t idx = td ? (c0 + ru*(c1 + ru*(c2 + ru*c3)))
                          : (c0 ^ (c1*2654435761u) ^ (c2*805459861u) ^ (c3*3674653429u));
        float2 e = tt2[idx & TMASK]; t0 += wt*e.x; t1 += wt*e.y;
    }
    size_t o = (size_t)n*32 + 2*(size_t)l;
    out[o] = s0 + t0*one_m; out[o+1] = s1 + t1*one_m;
}

extern "C" void kernel_launch(void* const* d_in, const int* in_sizes, int n_in,
                              void* d_out, int out_size, void* d_ws, size_t ws_size,
                              hipStream_t stream) {
    const float* x     = (const float*)d_in[0];
    const float* tab_s = (const float*)d_in[1];
    const float* tab_t = (const float*)d_in[2];
    const float* tab_m = (const float*)d_in[3];
    float* out = (float*)d_out;

    int N = in_sizes[0] / 4;                            // 400000
    size_t wm_b = (((size_t)N * 4) + 255) & ~(size_t)255;
    size_t wc_b = (size_t)N * NLEV * 8;                 // 51.2 MB
    size_t tb_b = (size_t)NLEV * (1u << 19) * 4;        // 33.55 MB per packed table
    int nchunk = (N + 255) / 256;

    if (ws_size >= wm_b + wc_b + 2 * tb_b) {
        float* wm = (float*)d_ws;
        f2v*   wc = (f2v*)((char*)d_ws + wm_b);
        uint32_t* ps = (uint32_t*)((char*)d_ws + wm_b + wc_b);
        uint32_t* pt = ps + (size_t)NLEV * (1u << 19);
        int half = NLEV * (1 << 19) / 2;                // f4 count per table
        int half_grid = 8 * nchunk;
        conv_kernel<<<(2 * half + 255) / 256, 256, 0, stream>>>(
            (const f4v*)tab_s, (const f4v*)tab_t, (u2v*)ps, (u2v*)pt, half);
        m_kernel<<<nchunk, 256, 0, stream>>>(x, tab_m, wm, N);
        enc_kernel<true><<<16 * nchunk, 256, 0, stream>>>(x, pt, wm, wc, N, half_grid);
        enc_kernel<false><<<16 * nchunk, 256, 0, stream>>>(x, ps, wm, wc, N, half_grid);
        out_kernel<<<nchunk, 256, 0, stream>>>(wc, (f4v*)out, N);
    } else {
        int total = N * NLEV;
        grid_enc_kernel<<<(total + 255) / 256, 256, 0, stream>>>(x, tab_s, tab_t, tab_m, out, N);
    }
}